// Round 4
// baseline (383.216 us; speedup 1.0000x reference)
//
#include <hip/hip_runtime.h>
#include <hip/hip_bf16.h>
#include <cstdint>

#define NTOK 16384
#define DIM 512
#define NEXP 8
#define HID 1024
#define CAPACITY 5120

typedef __attribute__((ext_vector_type(8))) short bf16x8;
typedef __attribute__((ext_vector_type(4))) float f32x4;
typedef unsigned long long u64;

__device__ __forceinline__ unsigned short f2bf(float f) {
    unsigned u = __float_as_uint(f);
    unsigned r = (u + 0x7FFFu + ((u >> 16) & 1u)) >> 16;
    return (unsigned short)r;
}

#define GLDS16(gp, lp) __builtin_amdgcn_global_load_lds( \
    (const __attribute__((address_space(1))) void*)(gp), \
    (__attribute__((address_space(3))) void*)(lp), 16, 0, 0)

// ---------------- gating: wave per token, fp32 exact ----------------
__global__ __launch_bounds__(256) void gating_kernel(
    const float* __restrict__ x, const float* __restrict__ eps,
    const float* __restrict__ wg, const float* __restrict__ wn,
    const float* __restrict__ Wh, int4* __restrict__ rec)
{
    int w = threadIdx.x >> 6, lane = threadIdx.x & 63;
    int n = blockIdx.x * 4 + w;
    float ag[8], an[8];
#pragma unroll
    for (int e = 0; e < 8; ++e) { ag[e] = 0.f; an[e] = 0.f; }
    const float* xr = x + (size_t)n * DIM;
#pragma unroll
    for (int i = 0; i < DIM / 64; ++i) {
        int d = i * 64 + lane;
        float xv = xr[d];
        const float4* g4 = reinterpret_cast<const float4*>(wg + (size_t)d * 8);
        const float4* n4 = reinterpret_cast<const float4*>(wn + (size_t)d * 8);
        float4 a0 = g4[0], a1 = g4[1], b0 = n4[0], b1v = n4[1];
        ag[0] += xv * a0.x; ag[1] += xv * a0.y; ag[2] += xv * a0.z; ag[3] += xv * a0.w;
        ag[4] += xv * a1.x; ag[5] += xv * a1.y; ag[6] += xv * a1.z; ag[7] += xv * a1.w;
        an[0] += xv * b0.x; an[1] += xv * b0.y; an[2] += xv * b0.z; an[3] += xv * b0.w;
        an[4] += xv * b1v.x; an[5] += xv * b1v.y; an[6] += xv * b1v.z; an[7] += xv * b1v.w;
    }
#pragma unroll
    for (int off = 32; off; off >>= 1) {
#pragma unroll
        for (int e = 0; e < 8; ++e) {
            ag[e] += __shfl_xor(ag[e], off);
            an[e] += __shfl_xor(an[e], off);
        }
    }
    float noisy[8];
#pragma unroll
    for (int e = 0; e < 8; ++e) {
        float c = 0.f;
#pragma unroll
        for (int j = 0; j < 8; ++j) c += ag[j] * Wh[j * 8 + e];
        float v = an[e];
        float sp = fmaxf(v, 0.f) + log1pf(expf(-fabsf(v)));
        noisy[e] = c + eps[(size_t)n * 8 + e] * (sp + 1e-2f);
    }
    int i1 = 0; float v1 = noisy[0];
#pragma unroll
    for (int e = 1; e < 8; ++e) if (noisy[e] > v1) { v1 = noisy[e]; i1 = e; }
    int i2 = -1; float v2 = -3.4e38f;
#pragma unroll
    for (int e = 0; e < 8; ++e) if (e != i1 && noisy[e] > v2) { v2 = noisy[e]; i2 = e; }
    float ex = expf(v2 - v1);
    float den = 1.f + ex;
    float g1 = 1.f / den, g2 = ex / den;
    if (lane == 0)
        rec[n] = make_int4(i1 | (i2 << 8), __float_as_int(g1), __float_as_int(g2), 0);
}

// -------- rank/dispatch: single block, batch-order prefix counts --------
__global__ __launch_bounds__(1024) void rank_dispatch(
    const int4* __restrict__ rec, int* __restrict__ buf, float* __restrict__ gbuf,
    int* __restrict__ counts, const int* __restrict__ cap_p)
{
    int cap = *cap_p; if (cap > CAPACITY) cap = CAPACITY;
    __shared__ u64 wtot[16];
    __shared__ int wprefix[16][8];
    __shared__ int base[8];
    __shared__ int itertot[8];
    int tid = threadIdx.x, w = tid >> 6, lane = tid & 63;
    if (tid < 8) base[tid] = 0;
    __syncthreads();
    for (int it = 0; it < NTOK; it += 1024) {
        int n = it + tid;
        int4 r = rec[n];
        int e1 = r.x & 0xFF, e2 = (r.x >> 8) & 0xFF;
        float g1 = __int_as_float(r.y), g2 = __int_as_float(r.z);
        u64 m = (1ULL << (e1 * 8)) | (1ULL << (e2 * 8));
        u64 incl = m;
#pragma unroll
        for (int off = 1; off < 64; off <<= 1) {
            u64 v = __shfl_up(incl, off);
            if (lane >= off) incl += v;
        }
        if (lane == 63) wtot[w] = incl;
        __syncthreads();
        if (tid < 128) {
            int e = tid & 7, ww = tid >> 3;
            int s = 0;
            for (int j = 0; j < ww; ++j) s += (int)((wtot[j] >> (e * 8)) & 0xFF);
            wprefix[ww][e] = s;
            if (ww == 15) itertot[e] = s + (int)((wtot[15] >> (e * 8)) & 0xFF);
        }
        __syncthreads();
        u64 excl = incl - m;
        int r1 = base[e1] + wprefix[w][e1] + (int)((excl >> (e1 * 8)) & 0xFF);
        int r2 = base[e2] + wprefix[w][e2] + (int)((excl >> (e2 * 8)) & 0xFF);
        if (r1 < cap) { buf[e1 * CAPACITY + r1] = n; gbuf[e1 * CAPACITY + r1] = g1; }
        if (r2 < cap) { buf[e2 * CAPACITY + r2] = n; gbuf[e2 * CAPACITY + r2] = g2; }
        __syncthreads();
        if (tid < 8) base[tid] += itertot[tid];
        __syncthreads();
    }
    if (tid < 8) counts[tid] = min(base[tid], cap);
}

// ---------------- converts ----------------
__global__ __launch_bounds__(256) void cvt_x(const float* __restrict__ in,
                                             unsigned short* __restrict__ out, int n)
{
    int i = (blockIdx.x * 256 + threadIdx.x) * 8;
    if (i >= n) return;
    float4 a = *reinterpret_cast<const float4*>(in + i);
    float4 b = *reinterpret_cast<const float4*>(in + i + 4);
    int4 v;
    v.x = f2bf(a.x) | ((int)f2bf(a.y) << 16);
    v.y = f2bf(a.z) | ((int)f2bf(a.w) << 16);
    v.z = f2bf(b.x) | ((int)f2bf(b.y) << 16);
    v.w = f2bf(b.z) | ((int)f2bf(b.w) << 16);
    *reinterpret_cast<int4*>(out + i) = v;
}

// transpose+convert: in [Z][R][C] f32 -> out [Z][C][R] bf16
__global__ __launch_bounds__(256) void tcvt(const float* __restrict__ in,
                                            unsigned short* __restrict__ out, int R, int C)
{
    __shared__ float tile[32][33];
    int z = blockIdx.z;
    int c0 = blockIdx.x * 32, r0 = blockIdx.y * 32;
    int tx = threadIdx.x, ty = threadIdx.y;
    const float* inz = in + (size_t)z * R * C;
    unsigned short* outz = out + (size_t)z * R * C;
#pragma unroll
    for (int j = 0; j < 32; j += 8)
        tile[ty + j][tx] = inz[(size_t)(r0 + ty + j) * C + c0 + tx];
    __syncthreads();
#pragma unroll
    for (int j = 0; j < 32; j += 8)
        outz[(size_t)(c0 + ty + j) * R + r0 + tx] = f2bf(tile[tx][ty + j]);
}

// ---------------- grouped FFN GEMM ----------------
// 128x128 tile, BK=128, 4 waves (2x2). A fragments loaded global->reg directly
// (no LDS for A; works for gathered and linear rows). Only B staged to LDS
// (32KB single buffer, XOR-swizzled chunk^(row&15), conflict-free reads).
// Per iter: stage B(t) + issue A(t) reg loads -> barrier (drain) -> ds_read B
// + MFMA -> barrier. A latency hides under the B drain; LDS stays 32KB so
// 3+ blocks/CU keep inter-block overlap.
template <int GATHER>
__global__ __launch_bounds__(256) void ffn_gemm(
    const unsigned short* __restrict__ A, const unsigned short* __restrict__ Bt,
    const float* __restrict__ bias, unsigned short* __restrict__ Hout,
    float* __restrict__ Out, const int* __restrict__ buf,
    const float* __restrict__ gbuf, const int* __restrict__ counts,
    int Ka, int Nd)
{
    int tm = blockIdx.x, tn = blockIdx.y, e = blockIdx.z;
    int cnt = counts[e];
    if (tm * 128 >= cnt) return;
    int tid = threadIdx.x, w = tid >> 6, lane = tid & 63;
    int q = lane >> 4, rl = lane & 15;
    int ebase = e * CAPACITY;
    int wm = w >> 1, wn = w & 1;

    __shared__ __align__(16) char Bs[32768];  // 128 rows x 256B (128 bf16), swizzled

    // B staging: 8 chunks/thread; chunk p=(w*8+i)*64+lane; row=p>>4, kp=p&15;
    // source chunk pre-swizzled c = kp ^ (row&15); LDS dest is linear (p*16).
    size_t boff[8];
#pragma unroll
    for (int i = 0; i < 8; ++i) {
        int p = (w * 8 + i) * 64 + lane;
        int row = p >> 4, kp = p & 15;
        int c = kp ^ (row & 15);
        boff[i] = (size_t)(e * Nd + tn * 128 + row) * Ka + c * 8;
    }

    // A row base pointers for this lane's 4 fragment rows
    const unsigned short* arow[4];
#pragma unroll
    for (int mi = 0; mi < 4; ++mi) {
        int slot = tm * 128 + wm * 64 + mi * 16 + rl;
        size_t r;
        if (GATHER) {
            int tok = (slot < cnt) ? buf[ebase + slot] : 0;
            r = (size_t)tok;
        } else {
            r = (size_t)(ebase + slot);
        }
        arow[mi] = A + r * Ka;
    }

    f32x4 acc[4][4];
#pragma unroll
    for (int mi = 0; mi < 4; ++mi)
#pragma unroll
        for (int ni = 0; ni < 4; ++ni)
            acc[mi][ni] = (f32x4){0.f, 0.f, 0.f, 0.f};

    int nk = Ka >> 7;  // BK=128

    for (int t = 0; t < nk; ++t) {
        int k0 = t * 128;
        // 1) stage B tile t into LDS (async DMA)
#pragma unroll
        for (int i = 0; i < 8; ++i)
            GLDS16(Bt + boff[i] + k0, Bs + (w * 8 + i) * 1024);
        // 2) issue A fragment loads global->reg (latency hides under B drain)
        bf16x8 af[4][4];
#pragma unroll
        for (int kk = 0; kk < 4; ++kk)
#pragma unroll
            for (int mi = 0; mi < 4; ++mi)
                af[kk][mi] = *reinterpret_cast<const bf16x8*>(arow[mi] + k0 + (kk * 4 + q) * 8);
        // 3) drain B DMA (and A loads) + sync
        __syncthreads();
        // 4) ds_read B frags + MFMA, 4 K=32 slices
#pragma unroll
        for (int kk = 0; kk < 4; ++kk) {
            bf16x8 bfr[4];
#pragma unroll
            for (int ni = 0; ni < 4; ++ni) {
                int row = wn * 64 + ni * 16 + rl;
                int cc = (kk * 4 + q) ^ (row & 15);
                bfr[ni] = *reinterpret_cast<const bf16x8*>(Bs + row * 256 + cc * 16);
            }
#pragma unroll
            for (int mi = 0; mi < 4; ++mi)
#pragma unroll
                for (int ni = 0; ni < 4; ++ni)
                    acc[mi][ni] = __builtin_amdgcn_mfma_f32_16x16x32_bf16(
                        af[kk][mi], bfr[ni], acc[mi][ni], 0, 0, 0);
        }
        // 5) all reads done before next stage overwrites Bs
        __syncthreads();
    }

    if (GATHER) {
#pragma unroll
        for (int ni = 0; ni < 4; ++ni) {
            int gcol = tn * 128 + wn * 64 + ni * 16 + rl;
            float bv = bias[e * Nd + gcol];
#pragma unroll
            for (int mi = 0; mi < 4; ++mi) {
#pragma unroll
                for (int r = 0; r < 4; ++r) {
                    int grow = tm * 128 + wm * 64 + mi * 16 + q * 4 + r;
                    float v = fmaxf(acc[mi][ni][r] + bv, 0.f);
                    Hout[(size_t)(ebase + grow) * HID + gcol] = f2bf(v);
                }
            }
        }
    } else {
#pragma unroll
        for (int ni = 0; ni < 4; ++ni) {
            int gcol = tn * 128 + wn * 64 + ni * 16 + rl;
            float bv = bias[e * Nd + gcol];
#pragma unroll
            for (int mi = 0; mi < 4; ++mi) {
#pragma unroll
                for (int r = 0; r < 4; ++r) {
                    int grow = tm * 128 + wm * 64 + mi * 16 + q * 4 + r;
                    if (grow < cnt) {
                        int tok = buf[ebase + grow];
                        float g = gbuf[ebase + grow];
                        float v = (acc[mi][ni][r] + bv) * g;
                        atomicAdd(Out + (size_t)tok * DIM + gcol, v);
                    }
                }
            }
        }
    }
}

extern "C" void kernel_launch(void* const* d_in, const int* in_sizes, int n_in,
                              void* d_out, int out_size, void* d_ws, size_t ws_size,
                              hipStream_t stream)
{
    const float* x   = (const float*)d_in[0];
    const float* eps = (const float*)d_in[1];
    const float* wg  = (const float*)d_in[2];
    const float* wn  = (const float*)d_in[3];
    const float* Wh  = (const float*)d_in[4];
    const float* W1  = (const float*)d_in[5];
    const float* b1  = (const float*)d_in[6];
    const float* W2  = (const float*)d_in[7];
    const float* b2  = (const float*)d_in[8];
    const int* capp  = (const int*)d_in[10];

    char* ws = (char*)d_ws;
    unsigned short* xg   = (unsigned short*)(ws);                 // 16 MB
    unsigned short* w1t  = (unsigned short*)(ws + 16777216);      // 8 MB  [E][HID][DIM]
    unsigned short* w2t  = (unsigned short*)(ws + 25165824);      // 8 MB  [E][DIM][HID]
    unsigned short* hbuf = (unsigned short*)(ws + 33554432);      // 80 MB [E*CAP][HID]
    int*   buf    = (int*)(ws + 117440512);                       // 160 KB
    float* gbuf   = (float*)(ws + 117604352);                     // 160 KB
    int4*  rec    = (int4*)(ws + 117768192);                      // 256 KB
    int*   counts = (int*)(ws + 118030336);

    float* out = (float*)d_out;
    hipMemsetAsync(out, 0, (size_t)out_size * sizeof(float), stream);

    gating_kernel<<<NTOK / 4, 256, 0, stream>>>(x, eps, wg, wn, Wh, rec);
    rank_dispatch<<<1, 1024, 0, stream>>>(rec, buf, gbuf, counts, capp);
    cvt_x<<<NTOK * DIM / 8 / 256, 256, 0, stream>>>(x, xg, NTOK * DIM);
    tcvt<<<dim3(HID / 32, DIM / 32, NEXP), dim3(32, 8), 0, stream>>>(W1, w1t, DIM, HID);
    tcvt<<<dim3(DIM / 32, HID / 32, NEXP), dim3(32, 8), 0, stream>>>(W2, w2t, HID, DIM);
    ffn_gemm<1><<<dim3(CAPACITY / 128, HID / 128, NEXP), 256, 0, stream>>>(
        xg, w1t, b1, hbuf, nullptr, buf, gbuf, counts, DIM, HID);
    ffn_gemm<0><<<dim3(CAPACITY / 128, DIM / 128, NEXP), 256, 0, stream>>>(
        hbuf, w2t, b2, nullptr, out, buf, gbuf, counts, HID, DIM);
}

// Round 5
// 351.657 us; speedup vs baseline: 1.0897x; 1.0897x over previous
//
#include <hip/hip_runtime.h>
#include <hip/hip_bf16.h>
#include <cstdint>

#define NTOK 16384
#define DIM 512
#define NEXP 8
#define HID 1024
#define CAPACITY 5120

typedef __attribute__((ext_vector_type(8))) short bf16x8;
typedef __attribute__((ext_vector_type(4))) float f32x4;
typedef unsigned long long u64;

__device__ __forceinline__ unsigned short f2bf(float f) {
    unsigned u = __float_as_uint(f);
    unsigned r = (u + 0x7FFFu + ((u >> 16) & 1u)) >> 16;
    return (unsigned short)r;
}

#define GLDS16(gp, lp) __builtin_amdgcn_global_load_lds( \
    (const __attribute__((address_space(1))) void*)(gp), \
    (__attribute__((address_space(3))) void*)(lp), 16, 0, 0)

// ---------------- gating: wave per token, fp32 exact ----------------
__global__ __launch_bounds__(256) void gating_kernel(
    const float* __restrict__ x, const float* __restrict__ eps,
    const float* __restrict__ wg, const float* __restrict__ wn,
    const float* __restrict__ Wh, int4* __restrict__ rec)
{
    int w = threadIdx.x >> 6, lane = threadIdx.x & 63;
    int n = blockIdx.x * 4 + w;
    float ag[8], an[8];
#pragma unroll
    for (int e = 0; e < 8; ++e) { ag[e] = 0.f; an[e] = 0.f; }
    const float* xr = x + (size_t)n * DIM;
#pragma unroll
    for (int i = 0; i < DIM / 64; ++i) {
        int d = i * 64 + lane;
        float xv = xr[d];
        const float4* g4 = reinterpret_cast<const float4*>(wg + (size_t)d * 8);
        const float4* n4 = reinterpret_cast<const float4*>(wn + (size_t)d * 8);
        float4 a0 = g4[0], a1 = g4[1], b0 = n4[0], b1v = n4[1];
        ag[0] += xv * a0.x; ag[1] += xv * a0.y; ag[2] += xv * a0.z; ag[3] += xv * a0.w;
        ag[4] += xv * a1.x; ag[5] += xv * a1.y; ag[6] += xv * a1.z; ag[7] += xv * a1.w;
        an[0] += xv * b0.x; an[1] += xv * b0.y; an[2] += xv * b0.z; an[3] += xv * b0.w;
        an[4] += xv * b1v.x; an[5] += xv * b1v.y; an[6] += xv * b1v.z; an[7] += xv * b1v.w;
    }
#pragma unroll
    for (int off = 32; off; off >>= 1) {
#pragma unroll
        for (int e = 0; e < 8; ++e) {
            ag[e] += __shfl_xor(ag[e], off);
            an[e] += __shfl_xor(an[e], off);
        }
    }
    float noisy[8];
#pragma unroll
    for (int e = 0; e < 8; ++e) {
        float c = 0.f;
#pragma unroll
        for (int j = 0; j < 8; ++j) c += ag[j] * Wh[j * 8 + e];
        float v = an[e];
        float sp = fmaxf(v, 0.f) + log1pf(expf(-fabsf(v)));
        noisy[e] = c + eps[(size_t)n * 8 + e] * (sp + 1e-2f);
    }
    int i1 = 0; float v1 = noisy[0];
#pragma unroll
    for (int e = 1; e < 8; ++e) if (noisy[e] > v1) { v1 = noisy[e]; i1 = e; }
    int i2 = -1; float v2 = -3.4e38f;
#pragma unroll
    for (int e = 0; e < 8; ++e) if (e != i1 && noisy[e] > v2) { v2 = noisy[e]; i2 = e; }
    float ex = expf(v2 - v1);
    float den = 1.f + ex;
    float g1 = 1.f / den, g2 = ex / den;
    if (lane == 0)
        rec[n] = make_int4(i1 | (i2 << 8), __float_as_int(g1), __float_as_int(g2), 0);
}

// -------- rank/dispatch: single block, batch-order prefix counts --------
__global__ __launch_bounds__(1024) void rank_dispatch(
    const int4* __restrict__ rec, int* __restrict__ buf, float* __restrict__ gbuf,
    int* __restrict__ counts, const int* __restrict__ cap_p)
{
    int cap = *cap_p; if (cap > CAPACITY) cap = CAPACITY;
    __shared__ u64 wtot[16];
    __shared__ int wprefix[16][8];
    __shared__ int base[8];
    __shared__ int itertot[8];
    int tid = threadIdx.x, w = tid >> 6, lane = tid & 63;
    if (tid < 8) base[tid] = 0;
    __syncthreads();
    for (int it = 0; it < NTOK; it += 1024) {
        int n = it + tid;
        int4 r = rec[n];
        int e1 = r.x & 0xFF, e2 = (r.x >> 8) & 0xFF;
        float g1 = __int_as_float(r.y), g2 = __int_as_float(r.z);
        u64 m = (1ULL << (e1 * 8)) | (1ULL << (e2 * 8));
        u64 incl = m;
#pragma unroll
        for (int off = 1; off < 64; off <<= 1) {
            u64 v = __shfl_up(incl, off);
            if (lane >= off) incl += v;
        }
        if (lane == 63) wtot[w] = incl;
        __syncthreads();
        if (tid < 128) {
            int e = tid & 7, ww = tid >> 3;
            int s = 0;
            for (int j = 0; j < ww; ++j) s += (int)((wtot[j] >> (e * 8)) & 0xFF);
            wprefix[ww][e] = s;
            if (ww == 15) itertot[e] = s + (int)((wtot[15] >> (e * 8)) & 0xFF);
        }
        __syncthreads();
        u64 excl = incl - m;
        int r1 = base[e1] + wprefix[w][e1] + (int)((excl >> (e1 * 8)) & 0xFF);
        int r2 = base[e2] + wprefix[w][e2] + (int)((excl >> (e2 * 8)) & 0xFF);
        if (r1 < cap) { buf[e1 * CAPACITY + r1] = n; gbuf[e1 * CAPACITY + r1] = g1; }
        if (r2 < cap) { buf[e2 * CAPACITY + r2] = n; gbuf[e2 * CAPACITY + r2] = g2; }
        __syncthreads();
        if (tid < 8) base[tid] += itertot[tid];
        __syncthreads();
    }
    if (tid < 8) counts[tid] = min(base[tid], cap);
}

// ---------------- converts ----------------
__global__ __launch_bounds__(256) void cvt_x(const float* __restrict__ in,
                                             unsigned short* __restrict__ out, int n)
{
    int i = (blockIdx.x * 256 + threadIdx.x) * 8;
    if (i >= n) return;
    float4 a = *reinterpret_cast<const float4*>(in + i);
    float4 b = *reinterpret_cast<const float4*>(in + i + 4);
    int4 v;
    v.x = f2bf(a.x) | ((int)f2bf(a.y) << 16);
    v.y = f2bf(a.z) | ((int)f2bf(a.w) << 16);
    v.z = f2bf(b.x) | ((int)f2bf(b.y) << 16);
    v.w = f2bf(b.z) | ((int)f2bf(b.w) << 16);
    *reinterpret_cast<int4*>(out + i) = v;
}

// transpose+convert: in [Z][R][C] f32 -> out [Z][C][R] bf16
__global__ __launch_bounds__(256) void tcvt(const float* __restrict__ in,
                                            unsigned short* __restrict__ out, int R, int C)
{
    __shared__ float tile[32][33];
    int z = blockIdx.z;
    int c0 = blockIdx.x * 32, r0 = blockIdx.y * 32;
    int tx = threadIdx.x, ty = threadIdx.y;
    const float* inz = in + (size_t)z * R * C;
    unsigned short* outz = out + (size_t)z * R * C;
#pragma unroll
    for (int j = 0; j < 32; j += 8)
        tile[ty + j][tx] = inz[(size_t)(r0 + ty + j) * C + c0 + tx];
    __syncthreads();
#pragma unroll
    for (int j = 0; j < 32; j += 8)
        outz[(size_t)(c0 + ty + j) * R + r0 + tx] = f2bf(tile[tx][ty + j]);
}

// ============ grouped FFN GEMM: 256x256, BK=64, 8 waves, 8-phase T3+T4 ============
// LDS ring: 2 K-tile buffers x {A,B} x {M-half h} x {K-half kh} = 16 slots x 8KB.
// Slot layout: contiguous [128 rows][32 cols bf16] -> each wave ds_read_b128 of a
// fragment set covers a contiguous 1KB (conflict-free, no swizzle needed; DMA dest
// linear per m104). Phase p: quadrant (kk=(p>>1)&1, nih=p&1) of tile u (p<4) or
// v (p>=4); 16 MFMA. Stage schedule (1 STAGE=2 units=2 glds/thread per phase):
//   p0: v.A k1 | p1: v.B k1 | p2: u+2.A k0 | p3: u+2.B k0
//   p4: u+2.A k1 | p5: u+2.B k1 | p6: v+2.A k0 | p7: v+2.B k0
// vmcnt(8) at every odd phase certifies the next phase's 4 oldest loads while
// keeping 8 in flight (never drains to 0). Raw s_barrier (no implicit vmcnt(0)).

#define STAGE(TG, O, KH)                                                        \
  {                                                                             \
    int tcl_ = ((TG) < nk) ? (TG) : (nk - 1);                                   \
    size_t kofs_ = (size_t)tcl_ * 64 + (KH) * 32;                               \
    char* db_ = lds + ((TG) & 1) * 65536 + (O) * 32768 + (KH) * 8192 + w * 1024;\
    if ((O) == 0) {                                                             \
      GLDS16(A + aoff0 + kofs_, db_);                                           \
      GLDS16(A + aoff1 + kofs_, db_ + 16384);                                   \
    } else {                                                                    \
      GLDS16(Bt + boff0 + kofs_, db_);                                          \
      GLDS16(Bt + boff1 + kofs_, db_ + 16384);                                  \
    }                                                                           \
  }

#define DO_PHASE(P, STG_TG, STG_O, STG_KH)                                      \
  {                                                                             \
    constexpr int kk_ = ((P) >> 1) & 1;                                         \
    constexpr int nih_ = (P) & 1;                                               \
    const char* cb_ = lds + (((P) >= 4) ? 65536 : 0);                           \
    if constexpr (((P) & 1) == 0) {                                             \
      _Pragma("unroll")                                                         \
      for (int mi = 0; mi < 8; ++mi)                                            \
        af[mi] = *reinterpret_cast<const bf16x8*>(                              \
            cb_ + wm * 16384 + kk_ * 8192 + (mi * 16 + rl) * 64 + q * 16);      \
    }                                                                           \
    bf16x8 bfr_[2];                                                             \
    _Pragma("unroll")                                                           \
    for (int nl = 0; nl < 2; ++nl) {                                            \
      int r2_ = (wn & 1) * 64 + (nih_ * 2 + nl) * 16 + rl;                      \
      bfr_[nl] = *reinterpret_cast<const bf16x8*>(                              \
          cb_ + 32768 + (wn >> 1) * 16384 + kk_ * 8192 + r2_ * 64 + q * 16);    \
    }                                                                           \
    STAGE(STG_TG, STG_O, STG_KH);                                               \
    if constexpr (((P) & 1) == 1)                                               \
      asm volatile("s_waitcnt vmcnt(8)" ::: "memory");                          \
    __builtin_amdgcn_s_barrier();                                               \
    asm volatile("s_waitcnt lgkmcnt(0)" ::: "memory");                          \
    __builtin_amdgcn_sched_barrier(0);                                          \
    __builtin_amdgcn_s_setprio(1);                                              \
    _Pragma("unroll")                                                           \
    for (int mi = 0; mi < 8; ++mi)                                              \
      _Pragma("unroll")                                                         \
      for (int nl = 0; nl < 2; ++nl)                                            \
        acc[mi][nih_ * 2 + nl] = __builtin_amdgcn_mfma_f32_16x16x32_bf16(       \
            af[mi], bfr_[nl], acc[mi][nih_ * 2 + nl], 0, 0, 0);                 \
    __builtin_amdgcn_s_setprio(0);                                              \
    __builtin_amdgcn_sched_barrier(0);                                          \
    __builtin_amdgcn_s_barrier();                                               \
  }

template <int GATHER>
__global__ __launch_bounds__(512, 2) void ffn_gemm(
    const unsigned short* __restrict__ A, const unsigned short* __restrict__ Bt,
    const float* __restrict__ bias, unsigned short* __restrict__ Hout,
    float* __restrict__ Out, const int* __restrict__ buf,
    const float* __restrict__ gbuf, const int* __restrict__ counts,
    int Ka, int Nd)
{
    int tm = blockIdx.x, tn = blockIdx.y, e = blockIdx.z;
    int cnt = counts[e];
    if (tm * 256 >= cnt) return;
    int tid = threadIdx.x, w = tid >> 6, lane = tid & 63;
    int q = lane >> 4, rl = lane & 15;
    int ebase = e * CAPACITY;
    int wm = w >> 2, wn = w & 3;   // 2M x 4N wave grid; per-wave out 128x64

    __shared__ __align__(16) char lds[131072];

    // staging source bases (element offsets): this thread covers
    // row (tid>>2) of each 128-row half, col-chunk (tid&3)*8.
    int srow = tid >> 2;
    size_t colc = (size_t)(tid & 3) * 8;
    size_t aoff0, aoff1, boff0, boff1;
    {
        int s0 = tm * 256 + srow, s1 = s0 + 128;
        if (GATHER) {
            int t0 = (s0 < cnt) ? buf[ebase + s0] : 0;
            int t1 = (s1 < cnt) ? buf[ebase + s1] : 0;
            aoff0 = (size_t)t0 * Ka + colc;
            aoff1 = (size_t)t1 * Ka + colc;
        } else {
            aoff0 = (size_t)(ebase + s0) * Ka + colc;
            aoff1 = (size_t)(ebase + s1) * Ka + colc;
        }
        boff0 = (size_t)(e * Nd + tn * 256 + srow) * Ka + colc;
        boff1 = (size_t)(e * Nd + tn * 256 + 128 + srow) * Ka + colc;
    }

    f32x4 acc[8][4];
#pragma unroll
    for (int mi = 0; mi < 8; ++mi)
#pragma unroll
        for (int ni = 0; ni < 4; ++ni)
            acc[mi][ni] = (f32x4){0.f, 0.f, 0.f, 0.f};

    int nk = Ka >> 6;       // K-tiles (BK=64): 8 or 16
    int niter = nk >> 1;    // 2 K-tiles per iteration

    bf16x8 af[8];

    // prologue: tiles 0 (full) + 1 (k0 halves) = 12 loads, then partial wait
    STAGE(0, 0, 0); STAGE(0, 1, 0); STAGE(0, 0, 1); STAGE(0, 1, 1);
    STAGE(1, 0, 0); STAGE(1, 1, 0);
    asm volatile("s_waitcnt vmcnt(8)" ::: "memory");
    __builtin_amdgcn_s_barrier();

    for (int i = 0; i < niter; ++i) {
        int u = 2 * i;
        DO_PHASE(0, u + 1, 0, 1);
        DO_PHASE(1, u + 1, 1, 1);
        DO_PHASE(2, u + 2, 0, 0);
        DO_PHASE(3, u + 2, 1, 0);
        DO_PHASE(4, u + 2, 0, 1);
        DO_PHASE(5, u + 2, 1, 1);
        DO_PHASE(6, u + 3, 0, 0);
        DO_PHASE(7, u + 3, 1, 0);
    }

    if (GATHER) {
#pragma unroll
        for (int ni = 0; ni < 4; ++ni) {
            int gcol = tn * 256 + wn * 64 + ni * 16 + rl;
            float bv = bias[e * Nd + gcol];
#pragma unroll
            for (int mi = 0; mi < 8; ++mi) {
#pragma unroll
                for (int r = 0; r < 4; ++r) {
                    int grow = tm * 256 + wm * 128 + mi * 16 + q * 4 + r;
                    float v = fmaxf(acc[mi][ni][r] + bv, 0.f);
                    Hout[(size_t)(ebase + grow) * HID + gcol] = f2bf(v);
                }
            }
        }
    } else {
#pragma unroll
        for (int ni = 0; ni < 4; ++ni) {
            int gcol = tn * 256 + wn * 64 + ni * 16 + rl;
            float bv = bias[e * Nd + gcol];
#pragma unroll
            for (int mi = 0; mi < 8; ++mi) {
#pragma unroll
                for (int r = 0; r < 4; ++r) {
                    int grow = tm * 256 + wm * 128 + mi * 16 + q * 4 + r;
                    if (grow < cnt) {
                        int tok = buf[ebase + grow];
                        float g = gbuf[ebase + grow];
                        float v = (acc[mi][ni][r] + bv) * g;
                        atomicAdd(Out + (size_t)tok * DIM + gcol, v);
                    }
                }
            }
        }
    }
}

extern "C" void kernel_launch(void* const* d_in, const int* in_sizes, int n_in,
                              void* d_out, int out_size, void* d_ws, size_t ws_size,
                              hipStream_t stream)
{
    const float* x   = (const float*)d_in[0];
    const float* eps = (const float*)d_in[1];
    const float* wg  = (const float*)d_in[2];
    const float* wn  = (const float*)d_in[3];
    const float* Wh  = (const float*)d_in[4];
    const float* W1  = (const float*)d_in[5];
    const float* b1  = (const float*)d_in[6];
    const float* W2  = (const float*)d_in[7];
    const float* b2  = (const float*)d_in[8];
    const int* capp  = (const int*)d_in[10];

    char* ws = (char*)d_ws;
    unsigned short* xg   = (unsigned short*)(ws);                 // 16 MB
    unsigned short* w1t  = (unsigned short*)(ws + 16777216);      // 8 MB  [E][HID][DIM]
    unsigned short* w2t  = (unsigned short*)(ws + 25165824);      // 8 MB  [E][DIM][HID]
    unsigned short* hbuf = (unsigned short*)(ws + 33554432);      // 80 MB [E*CAP][HID]
    int*   buf    = (int*)(ws + 117440512);                       // 160 KB
    float* gbuf   = (float*)(ws + 117604352);                     // 160 KB
    int4*  rec    = (int4*)(ws + 117768192);                      // 256 KB
    int*   counts = (int*)(ws + 118030336);

    float* out = (float*)d_out;
    hipMemsetAsync(out, 0, (size_t)out_size * sizeof(float), stream);

    gating_kernel<<<NTOK / 4, 256, 0, stream>>>(x, eps, wg, wn, Wh, rec);
    rank_dispatch<<<1, 1024, 0, stream>>>(rec, buf, gbuf, counts, capp);
    cvt_x<<<NTOK * DIM / 8 / 256, 256, 0, stream>>>(x, xg, NTOK * DIM);
    tcvt<<<dim3(HID / 32, DIM / 32, NEXP), dim3(32, 8), 0, stream>>>(W1, w1t, DIM, HID);
    tcvt<<<dim3(DIM / 32, HID / 32, NEXP), dim3(32, 8), 0, stream>>>(W2, w2t, HID, DIM);
    ffn_gemm<1><<<dim3(CAPACITY / 256, HID / 256, NEXP), 512, 0, stream>>>(
        xg, w1t, b1, hbuf, nullptr, buf, gbuf, counts, DIM, HID);
    ffn_gemm<0><<<dim3(CAPACITY / 256, DIM / 256, NEXP), 512, 0, stream>>>(
        hbuf, w2t, b2, nullptr, out, buf, gbuf, counts, HID, DIM);
}

// Round 6
// 290.698 us; speedup vs baseline: 1.3183x; 1.2097x over previous
//
#include <hip/hip_runtime.h>
#include <hip/hip_bf16.h>
#include <cstdint>

#define NTOK 16384
#define DIM 512
#define NEXP 8
#define HID 1024
#define CAPACITY 5120

typedef __attribute__((ext_vector_type(8))) short bf16x8;
typedef __attribute__((ext_vector_type(4))) float f32x4;
typedef unsigned long long u64;

__device__ __forceinline__ unsigned short f2bf(float f) {
    unsigned u = __float_as_uint(f);
    unsigned r = (u + 0x7FFFu + ((u >> 16) & 1u)) >> 16;
    return (unsigned short)r;
}

#define GLDS16(gp, lp) __builtin_amdgcn_global_load_lds( \
    (const __attribute__((address_space(1))) void*)(gp), \
    (__attribute__((address_space(3))) void*)(lp), 16, 0, 0)

// ---------------- gating: wave per token, fp32 exact ----------------
__global__ __launch_bounds__(256) void gating_kernel(
    const float* __restrict__ x, const float* __restrict__ eps,
    const float* __restrict__ wg, const float* __restrict__ wn,
    const float* __restrict__ Wh, int4* __restrict__ rec)
{
    int w = threadIdx.x >> 6, lane = threadIdx.x & 63;
    int n = blockIdx.x * 4 + w;
    float ag[8], an[8];
#pragma unroll
    for (int e = 0; e < 8; ++e) { ag[e] = 0.f; an[e] = 0.f; }
    const float* xr = x + (size_t)n * DIM;
#pragma unroll
    for (int i = 0; i < DIM / 64; ++i) {
        int d = i * 64 + lane;
        float xv = xr[d];
        const float4* g4 = reinterpret_cast<const float4*>(wg + (size_t)d * 8);
        const float4* n4 = reinterpret_cast<const float4*>(wn + (size_t)d * 8);
        float4 a0 = g4[0], a1 = g4[1], b0 = n4[0], b1v = n4[1];
        ag[0] += xv * a0.x; ag[1] += xv * a0.y; ag[2] += xv * a0.z; ag[3] += xv * a0.w;
        ag[4] += xv * a1.x; ag[5] += xv * a1.y; ag[6] += xv * a1.z; ag[7] += xv * a1.w;
        an[0] += xv * b0.x; an[1] += xv * b0.y; an[2] += xv * b0.z; an[3] += xv * b0.w;
        an[4] += xv * b1v.x; an[5] += xv * b1v.y; an[6] += xv * b1v.z; an[7] += xv * b1v.w;
    }
#pragma unroll
    for (int off = 32; off; off >>= 1) {
#pragma unroll
        for (int e = 0; e < 8; ++e) {
            ag[e] += __shfl_xor(ag[e], off);
            an[e] += __shfl_xor(an[e], off);
        }
    }
    float noisy[8];
#pragma unroll
    for (int e = 0; e < 8; ++e) {
        float c = 0.f;
#pragma unroll
        for (int j = 0; j < 8; ++j) c += ag[j] * Wh[j * 8 + e];
        float v = an[e];
        float sp = fmaxf(v, 0.f) + log1pf(expf(-fabsf(v)));
        noisy[e] = c + eps[(size_t)n * 8 + e] * (sp + 1e-2f);
    }
    int i1 = 0; float v1 = noisy[0];
#pragma unroll
    for (int e = 1; e < 8; ++e) if (noisy[e] > v1) { v1 = noisy[e]; i1 = e; }
    int i2 = -1; float v2 = -3.4e38f;
#pragma unroll
    for (int e = 0; e < 8; ++e) if (e != i1 && noisy[e] > v2) { v2 = noisy[e]; i2 = e; }
    float ex = expf(v2 - v1);
    float den = 1.f + ex;
    float g1 = 1.f / den, g2 = ex / den;
    if (lane == 0)
        rec[n] = make_int4(i1 | (i2 << 8), __float_as_int(g1), __float_as_int(g2), 0);
}

// -------- rank/dispatch: single block, batch-order prefix counts --------
__global__ __launch_bounds__(1024) void rank_dispatch(
    const int4* __restrict__ rec, int* __restrict__ buf, float* __restrict__ gbuf,
    int* __restrict__ counts, const int* __restrict__ cap_p)
{
    int cap = *cap_p; if (cap > CAPACITY) cap = CAPACITY;
    __shared__ u64 wtot[16];
    __shared__ int wprefix[16][8];
    __shared__ int base[8];
    __shared__ int itertot[8];
    int tid = threadIdx.x, w = tid >> 6, lane = tid & 63;
    if (tid < 8) base[tid] = 0;
    __syncthreads();
    for (int it = 0; it < NTOK; it += 1024) {
        int n = it + tid;
        int4 r = rec[n];
        int e1 = r.x & 0xFF, e2 = (r.x >> 8) & 0xFF;
        float g1 = __int_as_float(r.y), g2 = __int_as_float(r.z);
        u64 m = (1ULL << (e1 * 8)) | (1ULL << (e2 * 8));
        u64 incl = m;
#pragma unroll
        for (int off = 1; off < 64; off <<= 1) {
            u64 v = __shfl_up(incl, off);
            if (lane >= off) incl += v;
        }
        if (lane == 63) wtot[w] = incl;
        __syncthreads();
        if (tid < 128) {
            int e = tid & 7, ww = tid >> 3;
            int s = 0;
            for (int j = 0; j < ww; ++j) s += (int)((wtot[j] >> (e * 8)) & 0xFF);
            wprefix[ww][e] = s;
            if (ww == 15) itertot[e] = s + (int)((wtot[15] >> (e * 8)) & 0xFF);
        }
        __syncthreads();
        u64 excl = incl - m;
        int r1 = base[e1] + wprefix[w][e1] + (int)((excl >> (e1 * 8)) & 0xFF);
        int r2 = base[e2] + wprefix[w][e2] + (int)((excl >> (e2 * 8)) & 0xFF);
        if (r1 < cap) { buf[e1 * CAPACITY + r1] = n; gbuf[e1 * CAPACITY + r1] = g1; }
        if (r2 < cap) { buf[e2 * CAPACITY + r2] = n; gbuf[e2 * CAPACITY + r2] = g2; }
        __syncthreads();
        if (tid < 8) base[tid] += itertot[tid];
        __syncthreads();
    }
    if (tid < 8) counts[tid] = min(base[tid], cap);
}

// ------- gather + bf16 convert: x_exp[e*CAP+r][:] = bf16(x[buf[e*CAP+r]][:]) -------
// Invalid slots (r >= counts[e]) are zero-filled (deterministic; never read buf there).
__global__ __launch_bounds__(256) void gather_x(
    const float* __restrict__ x, const int* __restrict__ buf,
    const int* __restrict__ counts, unsigned short* __restrict__ xe)
{
    int slot = blockIdx.x * 4 + (threadIdx.x >> 6);
    int d0 = (threadIdx.x & 63) * 8;
    int e = slot / CAPACITY, r = slot - e * CAPACITY;
    int4 v;
    if (r < counts[e]) {
        int tok = buf[slot];
        const float* src = x + (size_t)tok * DIM + d0;
        float4 a = *reinterpret_cast<const float4*>(src);
        float4 b = *reinterpret_cast<const float4*>(src + 4);
        v.x = f2bf(a.x) | ((int)f2bf(a.y) << 16);
        v.y = f2bf(a.z) | ((int)f2bf(a.w) << 16);
        v.z = f2bf(b.x) | ((int)f2bf(b.y) << 16);
        v.w = f2bf(b.z) | ((int)f2bf(b.w) << 16);
    } else {
        v = make_int4(0, 0, 0, 0);
    }
    *reinterpret_cast<int4*>(xe + (size_t)slot * DIM + d0) = v;
}

// ---------------- converts ----------------
__global__ __launch_bounds__(256) void cvt_x(const float* __restrict__ in,
                                             unsigned short* __restrict__ out, int n)
{
    int i = (blockIdx.x * 256 + threadIdx.x) * 8;
    if (i >= n) return;
    float4 a = *reinterpret_cast<const float4*>(in + i);
    float4 b = *reinterpret_cast<const float4*>(in + i + 4);
    int4 v;
    v.x = f2bf(a.x) | ((int)f2bf(a.y) << 16);
    v.y = f2bf(a.z) | ((int)f2bf(a.w) << 16);
    v.z = f2bf(b.x) | ((int)f2bf(b.y) << 16);
    v.w = f2bf(b.z) | ((int)f2bf(b.w) << 16);
    *reinterpret_cast<int4*>(out + i) = v;
}

// transpose+convert: in [Z][R][C] f32 -> out [Z][C][R] bf16
__global__ __launch_bounds__(256) void tcvt(const float* __restrict__ in,
                                            unsigned short* __restrict__ out, int R, int C)
{
    __shared__ float tile[32][33];
    int z = blockIdx.z;
    int c0 = blockIdx.x * 32, r0 = blockIdx.y * 32;
    int tx = threadIdx.x, ty = threadIdx.y;
    const float* inz = in + (size_t)z * R * C;
    unsigned short* outz = out + (size_t)z * R * C;
#pragma unroll
    for (int j = 0; j < 32; j += 8)
        tile[ty + j][tx] = inz[(size_t)(r0 + ty + j) * C + c0 + tx];
    __syncthreads();
#pragma unroll
    for (int j = 0; j < 32; j += 8)
        outz[(size_t)(c0 + ty + j) * R + r0 + tx] = f2bf(tile[tx][ty + j]);
}

// ---------------- grouped FFN GEMM (R1-proven inner loop + XCD locality) ----------------
// 128x128 tile, BK=64, 4 waves (2x2), 32KB single-buffer LDS, XOR-swizzled staging
// (0 bank conflicts, verified R1). Block remap: e = flat&7 (expert pinned to XCD ->
// B L2-resident), tn fastest on each XCD (A-tile's N-sharers adjacent -> A fetched
// once into L2). MODE: 0 = linear A + scatter/atomic epilogue (GEMM2);
//                      1 = linear A + relu+b1 -> Hout  (GEMM1, dense x_exp);
//                      2 = gathered A (xg via buf) + relu+b1 -> Hout (GEMM1 fallback).
template <int MODE>
__global__ __launch_bounds__(256) void ffn_gemm(
    const unsigned short* __restrict__ A, const unsigned short* __restrict__ Bt,
    const float* __restrict__ bias, unsigned short* __restrict__ Hout,
    float* __restrict__ Out, const int* __restrict__ buf,
    const float* __restrict__ gbuf, const int* __restrict__ counts,
    int Ka, int Nd)
{
    // XCD-pinned bijective remap (dispatch round-robins flat%8 across XCDs)
    int flat = blockIdx.x + gridDim.x * (blockIdx.y + gridDim.y * blockIdx.z);
    int e  = flat & 7;
    int rr = flat >> 3;
    int tn = rr % gridDim.y;
    int tm = rr / gridDim.y;

    int cnt = counts[e];
    if (tm * 128 >= cnt) return;
    int tid = threadIdx.x, w = tid >> 6, lane = tid & 63;
    int q = lane >> 4, rl = lane & 15;
    int ebase = e * CAPACITY;

    __shared__ __align__(16) char lds[32768];
    char* As = lds;
    char* Bs = lds + 16384;

    // staging source offsets (elements), excluding k0
    unsigned aoff[4], boff[4];
#pragma unroll
    for (int i = 0; i < 4; ++i) {
        int p = (w * 4 + i) * 64 + lane;
        int row = p >> 3, kp = p & 7;
        int c = kp ^ (row & 7);
        int slot = tm * 128 + row;
        if (MODE == 2) {
            int tok = (slot < cnt) ? buf[ebase + slot] : 0;
            aoff[i] = (unsigned)tok * Ka + c * 8;
        } else {
            aoff[i] = (unsigned)(ebase + slot) * Ka + c * 8;
        }
        boff[i] = (unsigned)(e * Nd + tn * 128 + row) * Ka + c * 8;
    }

    f32x4 acc[4][4];
#pragma unroll
    for (int mi = 0; mi < 4; ++mi)
#pragma unroll
        for (int ni = 0; ni < 4; ++ni)
            acc[mi][ni] = (f32x4){0.f, 0.f, 0.f, 0.f};

    int wm = w >> 1, wn = w & 1;

    for (int k0 = 0; k0 < Ka; k0 += 64) {
#pragma unroll
        for (int i = 0; i < 4; ++i) {
            GLDS16(A + aoff[i] + k0, As + (w * 4 + i) * 1024);
            GLDS16(Bt + boff[i] + k0, Bs + (w * 4 + i) * 1024);
        }
        __syncthreads();
#pragma unroll
        for (int kk = 0; kk < 2; ++kk) {
            bf16x8 af[4], bfr[4];
#pragma unroll
            for (int mi = 0; mi < 4; ++mi) {
                int row = wm * 64 + mi * 16 + rl;
                int cc = (kk * 4 + q) ^ (row & 7);
                af[mi] = *reinterpret_cast<const bf16x8*>(As + row * 128 + cc * 16);
            }
#pragma unroll
            for (int ni = 0; ni < 4; ++ni) {
                int row = wn * 64 + ni * 16 + rl;
                int cc = (kk * 4 + q) ^ (row & 7);
                bfr[ni] = *reinterpret_cast<const bf16x8*>(Bs + row * 128 + cc * 16);
            }
#pragma unroll
            for (int mi = 0; mi < 4; ++mi)
#pragma unroll
                for (int ni = 0; ni < 4; ++ni)
                    acc[mi][ni] = __builtin_amdgcn_mfma_f32_16x16x32_bf16(
                        af[mi], bfr[ni], acc[mi][ni], 0, 0, 0);
        }
        __syncthreads();
    }

    if (MODE != 0) {
#pragma unroll
        for (int ni = 0; ni < 4; ++ni) {
            int gcol = tn * 128 + wn * 64 + ni * 16 + rl;
            float bv = bias[e * Nd + gcol];
#pragma unroll
            for (int mi = 0; mi < 4; ++mi) {
#pragma unroll
                for (int r = 0; r < 4; ++r) {
                    int grow = tm * 128 + wm * 64 + mi * 16 + q * 4 + r;
                    float v = fmaxf(acc[mi][ni][r] + bv, 0.f);
                    Hout[(size_t)(ebase + grow) * HID + gcol] = f2bf(v);
                }
            }
        }
    } else {
#pragma unroll
        for (int ni = 0; ni < 4; ++ni) {
            int gcol = tn * 128 + wn * 64 + ni * 16 + rl;
            float bv = bias[e * Nd + gcol];
#pragma unroll
            for (int mi = 0; mi < 4; ++mi) {
#pragma unroll
                for (int r = 0; r < 4; ++r) {
                    int grow = tm * 128 + wm * 64 + mi * 16 + q * 4 + r;
                    if (grow < cnt) {
                        int tok = buf[ebase + grow];
                        float g = gbuf[ebase + grow];
                        float v = (acc[mi][ni][r] + bv) * g;
                        atomicAdd(Out + (size_t)tok * DIM + gcol, v);
                    }
                }
            }
        }
    }
}

extern "C" void kernel_launch(void* const* d_in, const int* in_sizes, int n_in,
                              void* d_out, int out_size, void* d_ws, size_t ws_size,
                              hipStream_t stream)
{
    const float* x   = (const float*)d_in[0];
    const float* eps = (const float*)d_in[1];
    const float* wg  = (const float*)d_in[2];
    const float* wn  = (const float*)d_in[3];
    const float* Wh  = (const float*)d_in[4];
    const float* W1  = (const float*)d_in[5];
    const float* b1  = (const float*)d_in[6];
    const float* W2  = (const float*)d_in[7];
    const float* b2  = (const float*)d_in[8];
    const int* capp  = (const int*)d_in[10];

    // Layout: region0 (x_exp 41.94 MB dense path, or xg 16 MB fallback) | w1t 8MB |
    //         w2t 8MB | hbuf 80MB | buf | gbuf | rec | counts
    const size_t SZ_XEXP = (size_t)NEXP * CAPACITY * DIM * 2;   // 41,943,040
    const size_t SZ_XG   = (size_t)NTOK * DIM * 2;              // 16,777,216
    const size_t SZ_W1T  = (size_t)NEXP * DIM * HID * 2;        // 8,388,608
    const size_t SZ_W2T  = SZ_W1T;
    const size_t SZ_HBUF = (size_t)NEXP * CAPACITY * HID * 2;   // 83,886,080
    const size_t NEED_DENSE = SZ_XEXP + SZ_W1T + SZ_W2T + SZ_HBUF + 600000;
    bool dense = (ws_size >= NEED_DENSE);
    size_t sz0 = dense ? SZ_XEXP : SZ_XG;

    char* ws = (char*)d_ws;
    unsigned short* reg0 = (unsigned short*)(ws);
    unsigned short* w1t  = (unsigned short*)(ws + sz0);
    unsigned short* w2t  = (unsigned short*)(ws + sz0 + SZ_W1T);
    unsigned short* hbuf = (unsigned short*)(ws + sz0 + SZ_W1T + SZ_W2T);
    char* tail = ws + sz0 + SZ_W1T + SZ_W2T + SZ_HBUF;
    int*   buf    = (int*)(tail);
    float* gbuf   = (float*)(tail + 163840);
    int4*  rec    = (int4*)(tail + 327680);
    int*   counts = (int*)(tail + 589824);

    float* out = (float*)d_out;
    hipMemsetAsync(out, 0, (size_t)out_size * sizeof(float), stream);

    gating_kernel<<<NTOK / 4, 256, 0, stream>>>(x, eps, wg, wn, Wh, rec);
    rank_dispatch<<<1, 1024, 0, stream>>>(rec, buf, gbuf, counts, capp);
    tcvt<<<dim3(HID / 32, DIM / 32, NEXP), dim3(32, 8), 0, stream>>>(W1, w1t, DIM, HID);
    tcvt<<<dim3(DIM / 32, HID / 32, NEXP), dim3(32, 8), 0, stream>>>(W2, w2t, HID, DIM);

    if (dense) {
        gather_x<<<NEXP * CAPACITY / 4, 256, 0, stream>>>(x, buf, counts, reg0);
        ffn_gemm<1><<<dim3(CAPACITY / 128, HID / 128, NEXP), 256, 0, stream>>>(
            reg0, w1t, b1, hbuf, nullptr, buf, gbuf, counts, DIM, HID);
    } else {
        cvt_x<<<NTOK * DIM / 8 / 256, 256, 0, stream>>>(x, reg0, NTOK * DIM);
        ffn_gemm<2><<<dim3(CAPACITY / 128, HID / 128, NEXP), 256, 0, stream>>>(
            reg0, w1t, b1, hbuf, nullptr, buf, gbuf, counts, DIM, HID);
    }
    ffn_gemm<0><<<dim3(CAPACITY / 128, DIM / 128, NEXP), 256, 0, stream>>>(
        hbuf, w2t, b2, nullptr, out, buf, gbuf, counts, HID, DIM);
}

// Round 7
// 273.426 us; speedup vs baseline: 1.4015x; 1.0632x over previous
//
#include <hip/hip_runtime.h>
#include <hip/hip_bf16.h>
#include <cstdint>

#define NTOK 16384
#define DIM 512
#define NEXP 8
#define HID 1024
#define CAPACITY 5120

typedef __attribute__((ext_vector_type(8))) short bf16x8;
typedef __attribute__((ext_vector_type(4))) float f32x4;
typedef unsigned long long u64;

__device__ __forceinline__ unsigned short f2bf(float f) {
    unsigned u = __float_as_uint(f);
    unsigned r = (u + 0x7FFFu + ((u >> 16) & 1u)) >> 16;
    return (unsigned short)r;
}

#define GLDS16(gp, lp) __builtin_amdgcn_global_load_lds( \
    (const __attribute__((address_space(1))) void*)(gp), \
    (__attribute__((address_space(3))) void*)(lp), 16, 0, 0)

// ---------------- gating: wave per token, fp32 exact ----------------
__global__ __launch_bounds__(256) void gating_kernel(
    const float* __restrict__ x, const float* __restrict__ eps,
    const float* __restrict__ wg, const float* __restrict__ wn,
    const float* __restrict__ Wh, int2* __restrict__ rec)
{
    int w = threadIdx.x >> 6, lane = threadIdx.x & 63;
    int n = blockIdx.x * 4 + w;
    float ag[8], an[8];
#pragma unroll
    for (int e = 0; e < 8; ++e) { ag[e] = 0.f; an[e] = 0.f; }
    const float* xr = x + (size_t)n * DIM;
#pragma unroll
    for (int i = 0; i < DIM / 64; ++i) {
        int d = i * 64 + lane;
        float xv = xr[d];
        const float4* g4 = reinterpret_cast<const float4*>(wg + (size_t)d * 8);
        const float4* n4 = reinterpret_cast<const float4*>(wn + (size_t)d * 8);
        float4 a0 = g4[0], a1 = g4[1], b0 = n4[0], b1v = n4[1];
        ag[0] += xv * a0.x; ag[1] += xv * a0.y; ag[2] += xv * a0.z; ag[3] += xv * a0.w;
        ag[4] += xv * a1.x; ag[5] += xv * a1.y; ag[6] += xv * a1.z; ag[7] += xv * a1.w;
        an[0] += xv * b0.x; an[1] += xv * b0.y; an[2] += xv * b0.z; an[3] += xv * b0.w;
        an[4] += xv * b1v.x; an[5] += xv * b1v.y; an[6] += xv * b1v.z; an[7] += xv * b1v.w;
    }
#pragma unroll
    for (int off = 32; off; off >>= 1) {
#pragma unroll
        for (int e = 0; e < 8; ++e) {
            ag[e] += __shfl_xor(ag[e], off);
            an[e] += __shfl_xor(an[e], off);
        }
    }
    float noisy[8];
#pragma unroll
    for (int e = 0; e < 8; ++e) {
        float c = 0.f;
#pragma unroll
        for (int j = 0; j < 8; ++j) c += ag[j] * Wh[j * 8 + e];
        float v = an[e];
        float sp = fmaxf(v, 0.f) + log1pf(expf(-fabsf(v)));
        noisy[e] = c + eps[(size_t)n * 8 + e] * (sp + 1e-2f);
    }
    int i1 = 0; float v1 = noisy[0];
#pragma unroll
    for (int e = 1; e < 8; ++e) if (noisy[e] > v1) { v1 = noisy[e]; i1 = e; }
    int i2 = -1; float v2 = -3.4e38f;
#pragma unroll
    for (int e = 0; e < 8; ++e) if (e != i1 && noisy[e] > v2) { v2 = noisy[e]; i2 = e; }
    float ex = expf(v2 - v1);
    float g1 = 1.f / (1.f + ex);
    if (lane == 0)
        rec[n] = make_int2(i1 | (i2 << 8), __float_as_int(g1));
}

// ---- rank pass 1: per-1024-token-block local ranks + per-block expert totals ----
__global__ __launch_bounds__(1024) void scan_local(
    const int2* __restrict__ rec, unsigned* __restrict__ lrank, int* __restrict__ btot)
{
    __shared__ u64 wtot[16];
    __shared__ int wprefix[16][8];
    int tid = threadIdx.x, w = tid >> 6, lane = tid & 63;
    int n = blockIdx.x * 1024 + tid;
    int2 r = rec[n];
    int e1 = r.x & 0xFF, e2 = (r.x >> 8) & 0xFF;
    u64 m = (1ULL << (e1 * 8)) | (1ULL << (e2 * 8));
    u64 incl = m;
#pragma unroll
    for (int off = 1; off < 64; off <<= 1) {
        u64 v = __shfl_up(incl, off);
        if (lane >= off) incl += v;
    }
    if (lane == 63) wtot[w] = incl;
    __syncthreads();
    if (tid < 128) {
        int e = tid & 7, ww = tid >> 3;
        int s = 0;
        for (int j = 0; j < ww; ++j) s += (int)((wtot[j] >> (e * 8)) & 0xFF);
        wprefix[ww][e] = s;
        if (ww == 15)
            btot[blockIdx.x * 8 + e] = s + (int)((wtot[15] >> (e * 8)) & 0xFF);
    }
    __syncthreads();
    u64 excl = incl - m;
    unsigned l1 = (unsigned)(wprefix[w][e1] + (int)((excl >> (e1 * 8)) & 0xFF));
    unsigned l2 = (unsigned)(wprefix[w][e2] + (int)((excl >> (e2 * 8)) & 0xFF));
    lrank[n] = l1 | (l2 << 16);
}

// ---- rank pass 2: tiny exclusive scan of 16 block-totals per expert ----
__global__ __launch_bounds__(64) void scan_offs(
    const int* __restrict__ btot, int* __restrict__ off, int* __restrict__ counts,
    const int* __restrict__ cap_p)
{
    int e = threadIdx.x;
    if (e >= 8) return;
    int cap = *cap_p; if (cap > CAPACITY) cap = CAPACITY;
    int run = 0;
    for (int b = 0; b < 16; ++b) {
        off[b * 8 + e] = run;
        run += btot[b * 8 + e];
    }
    counts[e] = min(run, cap);
}

// ---- rank pass 3: scatter tokens into [E][CAPACITY] slots ----
__global__ __launch_bounds__(1024) void scatter_k(
    const int2* __restrict__ rec, const unsigned* __restrict__ lrank,
    const int* __restrict__ off, const int* __restrict__ cap_p,
    int* __restrict__ buf, float* __restrict__ gbuf)
{
    int tid = threadIdx.x, b = blockIdx.x;
    int n = b * 1024 + tid;
    int cap = *cap_p; if (cap > CAPACITY) cap = CAPACITY;
    int2 r = rec[n];
    int e1 = r.x & 0xFF, e2 = (r.x >> 8) & 0xFF;
    float g1 = __int_as_float(r.y), g2 = 1.f - g1;
    unsigned lr = lrank[n];
    int r1 = off[b * 8 + e1] + (int)(lr & 0xFFFF);
    int r2 = off[b * 8 + e2] + (int)(lr >> 16);
    if (r1 < cap) { buf[e1 * CAPACITY + r1] = n; gbuf[e1 * CAPACITY + r1] = g1; }
    if (r2 < cap) { buf[e2 * CAPACITY + r2] = n; gbuf[e2 * CAPACITY + r2] = g2; }
}

// ---- gather + convert + K-PACK: xe[e][kc][slot][8] = bf16(x[buf[slot]][kc*8..+8]) ----
// wave per slot; lane owns k-chunk `lane`. Reads 32B/lane coalesced; writes 16B/lane,
// 4 waves/block cover 4 consecutive slots -> adjacent 16B chunks combine into sectors.
__global__ __launch_bounds__(256) void gather_x(
    const float* __restrict__ x, const int* __restrict__ buf,
    const int* __restrict__ counts, unsigned short* __restrict__ xe)
{
    int slot = blockIdx.x * 4 + (threadIdx.x >> 6);
    int lane = threadIdx.x & 63;
    int e = slot / CAPACITY, rr = slot - e * CAPACITY;
    int4 v = make_int4(0, 0, 0, 0);
    if (rr < counts[e]) {
        int tok = buf[slot];
        const float* src = x + (size_t)tok * DIM + lane * 8;
        float4 a = *reinterpret_cast<const float4*>(src);
        float4 b = *reinterpret_cast<const float4*>(src + 4);
        v.x = f2bf(a.x) | ((int)f2bf(a.y) << 16);
        v.y = f2bf(a.z) | ((int)f2bf(a.w) << 16);
        v.z = f2bf(b.x) | ((int)f2bf(b.y) << 16);
        v.w = f2bf(b.z) | ((int)f2bf(b.w) << 16);
    }
    *reinterpret_cast<int4*>(xe + (size_t)e * CAPACITY * DIM +
                             ((size_t)lane * CAPACITY + rr) * 8) = v;
}

// transpose+convert: in [Z][R][C] f32 -> out [Z][C][R] bf16
__global__ __launch_bounds__(256) void tcvt(const float* __restrict__ in,
                                            unsigned short* __restrict__ out, int R, int C)
{
    __shared__ float tile[32][33];
    int z = blockIdx.z;
    int c0 = blockIdx.x * 32, r0 = blockIdx.y * 32;
    int tx = threadIdx.x, ty = threadIdx.y;
    const float* inz = in + (size_t)z * R * C;
    unsigned short* outz = out + (size_t)z * R * C;
#pragma unroll
    for (int j = 0; j < 32; j += 8)
        tile[ty + j][tx] = inz[(size_t)(r0 + ty + j) * C + c0 + tx];
    __syncthreads();
#pragma unroll
    for (int j = 0; j < 32; j += 8)
        outz[(size_t)(c0 + ty + j) * R + r0 + tx] = f2bf(tile[tx][ty + j]);
}

// ========== grouped FFN GEMM: 128x128, BK=64, 4 waves, counted-vmcnt pipeline ==========
// A: k-packed [e][kc][slot][8] -> direct global->reg, perfectly coalesced, no LDS.
// B: [e][outcol][k] row-major -> LDS double-buffer 2x16KB, R1-proven XOR swizzle.
// Per iter: stage B(t+1) (4 DMA) ; load A(t+1)->regs (8) ; vmcnt(12) ; s_barrier ;
//           ds_read B(t) + 32 MFMA ; s_barrier.   vmcnt never drains to 0 (T4).
// MODE 1: epilogue relu+b1 -> Hout k-packed [e][kc][slot][8] (feeds GEMM2 A).
// MODE 0: epilogue +b2, *gate, atomicAdd scatter -> Out.

#define STAGEB(T, BI)                                                      \
  {                                                                        \
    size_t k0_ = (size_t)(T) * 64;                                         \
    char* db_ = lds + (BI) * 16384 + w * 4096 + lane * 16;                 \
    GLDS16(Bt + boff[0] + k0_, db_);                                       \
    GLDS16(Bt + boff[1] + k0_, db_ + 1024);                                \
    GLDS16(Bt + boff[2] + k0_, db_ + 2048);                                \
    GLDS16(Bt + boff[3] + k0_, db_ + 3072);                                \
  }

#define LOADA(T, AF)                                                       \
  {                                                                        \
    const unsigned short* ab_ = A + abase + (size_t)(T) * (CAPACITY * 64); \
    _Pragma("unroll")                                                      \
    for (int kk = 0; kk < 2; ++kk)                                         \
      _Pragma("unroll")                                                    \
      for (int mi = 0; mi < 4; ++mi)                                       \
        AF[kk][mi] = *reinterpret_cast<const bf16x8*>(ab_ + voff[kk][mi]); \
  }

#define COMPUTE(BI, AF)                                                    \
  {                                                                        \
    const char* cb_ = lds + (BI) * 16384;                                  \
    _Pragma("unroll")                                                      \
    for (int kk = 0; kk < 2; ++kk) {                                       \
      bf16x8 bfr_[4];                                                      \
      _Pragma("unroll")                                                    \
      for (int ni = 0; ni < 4; ++ni) {                                     \
        int row_ = wn * 64 + ni * 16 + rl;                                 \
        int cc_ = (kk * 4 + q) ^ (row_ & 7);                               \
        bfr_[ni] = *reinterpret_cast<const bf16x8*>(cb_ + row_ * 128 + cc_ * 16); \
      }                                                                    \
      _Pragma("unroll")                                                    \
      for (int mi = 0; mi < 4; ++mi)                                       \
        _Pragma("unroll")                                                  \
        for (int ni = 0; ni < 4; ++ni)                                     \
          acc[mi][ni] = __builtin_amdgcn_mfma_f32_16x16x32_bf16(           \
              AF[kk][mi], bfr_[ni], acc[mi][ni], 0, 0, 0);                 \
    }                                                                      \
  }

#define VMCNT12 asm volatile("s_waitcnt vmcnt(12)" ::: "memory")
#define BARRIER asm volatile("s_barrier" ::: "memory")

template <int MODE>
__global__ __launch_bounds__(256) void ffn_gemm(
    const unsigned short* __restrict__ A, const unsigned short* __restrict__ Bt,
    const float* __restrict__ bias, unsigned short* __restrict__ Hout,
    float* __restrict__ Out, const int* __restrict__ buf,
    const float* __restrict__ gbuf, const int* __restrict__ counts,
    int Ka, int Nd)
{
    // XCD-pinned bijective remap (dispatch round-robins flat%8 across XCDs)
    int flat = blockIdx.x + gridDim.x * (blockIdx.y + gridDim.y * blockIdx.z);
    int e  = flat & 7;
    int rr = flat >> 3;
    int tn = rr % gridDim.y;
    int tm = rr / gridDim.y;

    int cnt = counts[e];
    if (tm * 128 >= cnt) return;
    int tid = threadIdx.x, w = tid >> 6, lane = tid & 63;
    int q = lane >> 4, rl = lane & 15;
    int wm = w >> 1, wn = w & 1;

    __shared__ __align__(16) char lds[32768];   // 2 x 16KB B double-buffer

    // B staging source offsets (elements, k excluded); R1 swizzle: c = kp^(row&7)
    unsigned boff[4];
#pragma unroll
    for (int i = 0; i < 4; ++i) {
        int p = (w * 4 + i) * 64 + lane;
        int row = p >> 3, kp = p & 7;
        int c = kp ^ (row & 7);
        boff[i] = (unsigned)(e * Nd + tn * 128 + row) * Ka + c * 8;
    }

    // A fragment voffsets (elements) within the k-packed expert region
    size_t abase = (size_t)e * CAPACITY * Ka;
    unsigned voff[2][4];
#pragma unroll
    for (int kk = 0; kk < 2; ++kk)
#pragma unroll
        for (int mi = 0; mi < 4; ++mi) {
            int row = tm * 128 + wm * 64 + mi * 16 + rl;
            voff[kk][mi] = (unsigned)((kk * 4 + q) * CAPACITY + row) * 8;
        }

    f32x4 acc[4][4];
#pragma unroll
    for (int mi = 0; mi < 4; ++mi)
#pragma unroll
        for (int ni = 0; ni < 4; ++ni)
            acc[mi][ni] = (f32x4){0.f, 0.f, 0.f, 0.f};

    int nk = Ka >> 6;   // 8 or 16 (even)

    bf16x8 afA[2][4], afB[2][4];

    // prologue: tile 0 -> buf0 + regs (12 VMEM in flight)
    STAGEB(0, 0);
    LOADA(0, afA);

    for (int t = 0; t < nk; t += 2) {
        {   // even: compute tile t (buf t&1=0-pattern), prefetch t+1
            int tp = (t + 1 < nk) ? t + 1 : nk - 1;
            STAGEB(tp, (t + 1) & 1);
            LOADA(tp, afB);
            VMCNT12; BARRIER;
            COMPUTE(t & 1, afA);
            BARRIER;
        }
        {   // odd: compute tile t+1, prefetch t+2
            int tp = (t + 2 < nk) ? t + 2 : nk - 1;
            STAGEB(tp, (t + 2) & 1);
            LOADA(tp, afA);
            VMCNT12; BARRIER;
            COMPUTE((t + 1) & 1, afB);
            BARRIER;
        }
    }

    if (MODE == 1) {
        // write h k-packed: [e][gcol>>3][slot][gcol&7]
        unsigned short* hb = Hout + (size_t)e * CAPACITY * HID;
#pragma unroll
        for (int ni = 0; ni < 4; ++ni) {
            int gcol = tn * 128 + wn * 64 + ni * 16 + rl;
            float bv = bias[e * Nd + gcol];
            size_t cb = ((size_t)(gcol >> 3) * CAPACITY) * 8 + (gcol & 7);
#pragma unroll
            for (int mi = 0; mi < 4; ++mi) {
#pragma unroll
                for (int r = 0; r < 4; ++r) {
                    int grow = tm * 128 + wm * 64 + mi * 16 + q * 4 + r;
                    float v = fmaxf(acc[mi][ni][r] + bv, 0.f);
                    hb[cb + (size_t)grow * 8] = f2bf(v);
                }
            }
        }
    } else {
        int ebase = e * CAPACITY;
#pragma unroll
        for (int ni = 0; ni < 4; ++ni) {
            int gcol = tn * 128 + wn * 64 + ni * 16 + rl;
            float bv = bias[e * Nd + gcol];
#pragma unroll
            for (int mi = 0; mi < 4; ++mi) {
#pragma unroll
                for (int r = 0; r < 4; ++r) {
                    int grow = tm * 128 + wm * 64 + mi * 16 + q * 4 + r;
                    if (grow < cnt) {
                        int tok = buf[ebase + grow];
                        float g = gbuf[ebase + grow];
                        float v = (acc[mi][ni][r] + bv) * g;
                        atomicAdd(Out + (size_t)tok * DIM + gcol, v);
                    }
                }
            }
        }
    }
}

extern "C" void kernel_launch(void* const* d_in, const int* in_sizes, int n_in,
                              void* d_out, int out_size, void* d_ws, size_t ws_size,
                              hipStream_t stream)
{
    const float* x   = (const float*)d_in[0];
    const float* eps = (const float*)d_in[1];
    const float* wg  = (const float*)d_in[2];
    const float* wn  = (const float*)d_in[3];
    const float* Wh  = (const float*)d_in[4];
    const float* W1  = (const float*)d_in[5];
    const float* b1  = (const float*)d_in[6];
    const float* W2  = (const float*)d_in[7];
    const float* b2  = (const float*)d_in[8];
    const int* capp  = (const int*)d_in[10];

    char* ws = (char*)d_ws;
    unsigned short* xe   = (unsigned short*)(ws);              // 41,943,040  k-packed x_exp
    unsigned short* w1t  = (unsigned short*)(ws + 41943040);   // 8,388,608   [E][HID][DIM]
    unsigned short* w2t  = (unsigned short*)(ws + 50331648);   // 8,388,608   [E][DIM][HID]
    unsigned short* hK   = (unsigned short*)(ws + 58720256);   // 83,886,080  k-packed h
    int*      buf    = (int*)     (ws + 142606336);            // 163,840
    float*    gbuf   = (float*)   (ws + 142770176);            // 163,840
    int2*     rec    = (int2*)    (ws + 142934016);            // 131,072
    unsigned* lrank  = (unsigned*)(ws + 143065088);            // 65,536
    int*      btot   = (int*)     (ws + 143130624);            // 512
    int*      off    = (int*)     (ws + 143131136);            // 512
    int*      counts = (int*)     (ws + 143131648);            // 32

    float* out = (float*)d_out;
    hipMemsetAsync(out, 0, (size_t)out_size * sizeof(float), stream);

    gating_kernel<<<NTOK / 4, 256, 0, stream>>>(x, eps, wg, wn, Wh, rec);
    scan_local<<<16, 1024, 0, stream>>>(rec, lrank, btot);
    scan_offs<<<1, 64, 0, stream>>>(btot, off, counts, capp);
    scatter_k<<<16, 1024, 0, stream>>>(rec, lrank, off, capp, buf, gbuf);
    tcvt<<<dim3(HID / 32, DIM / 32, NEXP), dim3(32, 8), 0, stream>>>(W1, w1t, DIM, HID);
    tcvt<<<dim3(DIM / 32, HID / 32, NEXP), dim3(32, 8), 0, stream>>>(W2, w2t, HID, DIM);
    gather_x<<<NEXP * CAPACITY / 4, 256, 0, stream>>>(x, buf, counts, xe);

    ffn_gemm<1><<<dim3(CAPACITY / 128, HID / 128, NEXP), 256, 0, stream>>>(
        xe, w1t, b1, hK, nullptr, buf, gbuf, counts, DIM, HID);
    ffn_gemm<0><<<dim3(CAPACITY / 128, DIM / 128, NEXP), 256, 0, stream>>>(
        hK, w2t, b2, nullptr, out, buf, gbuf, counts, HID, DIM);
}